// Round 5
// baseline (90.482 us; speedup 1.0000x reference)
//
#include <hip/hip_runtime.h>
#include <stdint.h>

#define LL   2048
#define DD   256
#define SLOTS 64
#define MN   192
#define PT   8192          // B*L

typedef _Float16 half8 __attribute__((ext_vector_type(8)));
typedef float    f32x4 __attribute__((ext_vector_type(4)));

#define FRAG_ELEMS (MN * DD)   // 49152 f16 elems per frag array

// ---------------- K0: fragment prep (same as R4, proven) ----------------
__global__ __launch_bounds__(256) void prep_kernel(
    const float* __restrict__ mem,
    _Float16* __restrict__ aS_h, _Float16* __restrict__ aS_l,
    _Float16* __restrict__ bG_h, _Float16* __restrict__ bG_l)
{
    const int e = blockIdx.x * 256 + threadIdx.x;   // grid 192 -> 49152
    const int mn = e >> 8;
    const int d  = e & 255;
    const float v = mem[e];
    const _Float16 h  = (_Float16)v;
    const _Float16 lo = (_Float16)(v - (float)h);

    // score GEMM A-frags: tiles of 16 mn, K-chunks of 32 d
    {
        const int tm = mn >> 4, r = mn & 15;
        const int c = d >> 5, q = (d >> 3) & 3, j = d & 7;
        const int i1 = ((tm * 8 + c) * 64 + (q * 16 + r)) * 8 + j;
        aS_h[i1] = h; aS_l[i1] = lo;
    }
    // select GEMM B-frags: K-chunks of 32 mn, d-tiles of 16
    {
        const int c2 = mn >> 5, q2 = (mn >> 3) & 3, j2 = mn & 7;
        const int td = d >> 4, n2 = d & 15;
        const int i2 = ((td * 6 + c2) * 64 + (q2 * 16 + n2)) * 8 + j2;
        bG_h[i2] = h; bG_l[i2] = lo;
    }
}

// ---------------- K1: score MFMA + argmax -> selection masks ----------------
// grid 512 x 256 thr. Block -> 16 output p rows; score window 32 rows.
__global__ __launch_bounds__(256) void score_sel_kernel(
    const float* __restrict__ x, const float* __restrict__ bias,
    const _Float16* __restrict__ aS_h, const _Float16* __restrict__ aS_l,
    uint32_t* __restrict__ sel_out)
{
    __shared__ _Float16 xfh[2 * 8 * 64 * 8];   // 16 KB
    __shared__ _Float16 xfl[2 * 8 * 64 * 8];   // 16 KB
    __shared__ float    scores[MN * 33];       // 25.3 KB
    __shared__ float    biasS[MN];
    __shared__ uint32_t selS[16 * 8];

    const int p0   = blockIdx.x * 16;
    const int tid  = threadIdx.x;
    const int lane = tid & 63;
    const int w    = tid >> 6;

    // ---- Phase A: stage x window -> f16 hi/lo B-frags in LDS ----
    if (tid < 128) selS[tid] = 0u;
    if (tid < MN)  biasS[tid] = bias[tid];
    {
        const int c  = tid & 7;
        const int rr = tid >> 3;       // window row 0..31
        int g = p0 - 2 + rr;
        g = g < 0 ? 0 : (g > PT - 1 ? PT - 1 : g);
        const float4* xr = (const float4*)(x + (size_t)g * DD + c * 32);
        const int pt = rr >> 4, lr = rr & 15;
#pragma unroll
        for (int q = 0; q < 4; ++q) {
            const float4 u = xr[q * 2];
            const float4 v = xr[q * 2 + 1];
            float f[8] = {u.x, u.y, u.z, u.w, v.x, v.y, v.z, v.w};
            half8 hi, lo;
#pragma unroll
            for (int j = 0; j < 8; ++j) {
                const _Float16 h = (_Float16)f[j];
                hi[j] = h;
                lo[j] = (_Float16)(f[j] - (float)h);
            }
            const int base = ((pt * 8 + c) * 64 + q * 16 + lr) * 8;
            *(half8*)(xfh + base) = hi;
            *(half8*)(xfl + base) = lo;
        }
    }
    __syncthreads();

    // ---- Phase B: score GEMM (wave w: mn-tiles 3w..3w+2 x 2 p-tiles) ----
    {
        f32x4 acc[3][2];
#pragma unroll
        for (int i = 0; i < 3; ++i)
#pragma unroll
            for (int p = 0; p < 2; ++p) acc[i][p] = (f32x4){0.f, 0.f, 0.f, 0.f};

#pragma unroll 2
        for (int c = 0; c < 8; ++c) {
            half8 ah[3], al[3], bh[2], bl[2];
#pragma unroll
            for (int i = 0; i < 3; ++i) {
                const int tm = w * 3 + i;
                const size_t off = (size_t)((tm * 8 + c) * 64 + lane) * 8;
                ah[i] = *(const half8*)(aS_h + off);
                al[i] = *(const half8*)(aS_l + off);
            }
#pragma unroll
            for (int p = 0; p < 2; ++p) {
                const int base = ((p * 8 + c) * 64 + lane) * 8;
                bh[p] = *(const half8*)(xfh + base);
                bl[p] = *(const half8*)(xfl + base);
            }
#pragma unroll
            for (int i = 0; i < 3; ++i)
#pragma unroll
                for (int p = 0; p < 2; ++p) {
                    acc[i][p] = __builtin_amdgcn_mfma_f32_16x16x32_f16(ah[i], bh[p], acc[i][p], 0, 0, 0);
                    acc[i][p] = __builtin_amdgcn_mfma_f32_16x16x32_f16(ah[i], bl[p], acc[i][p], 0, 0, 0);
                    acc[i][p] = __builtin_amdgcn_mfma_f32_16x16x32_f16(al[i], bh[p], acc[i][p], 0, 0, 0);
                }
        }

        const int q = lane >> 4, col = lane & 15;
#pragma unroll
        for (int i = 0; i < 3; ++i) {
            const int tm = w * 3 + i;
#pragma unroll
            for (int p = 0; p < 2; ++p) {
                const int wp = p * 16 + col;
#pragma unroll
                for (int r = 0; r < 4; ++r) {
                    const int mn = tm * 16 + q * 4 + r;
                    scores[mn * 33 + wp] = acc[i][p][r];
                }
            }
        }
    }
    __syncthreads();

    // ---- Phase C: argmax over n (first-max tiebreak) -> bitmask ----
#pragma unroll
    for (int it = 0; it < 4; ++it) {
        const int t2 = tid + it * 256;
        const int pl = t2 & 15;
        const int m  = t2 >> 4;
        const int p  = p0 + pl;
        const int l  = p & (LL - 1);
        const float v0 = ((l >= 2) ? scores[(3 * m + 0) * 33 + pl + 0] : 0.f) + biasS[3 * m + 0];
        const float v1 = ((l >= 1) ? scores[(3 * m + 1) * 33 + pl + 1] : 0.f) + biasS[3 * m + 1];
        const float v2 =              scores[(3 * m + 2) * 33 + pl + 2]       + biasS[3 * m + 2];
        int bn = 0; float bv = v0;
        if (v1 > bv) { bv = v1; bn = 1; }
        if (v2 > bv) { bv = v2; bn = 2; }
        const int mnb = 3 * m + bn;
        atomicOr(&selS[pl * 8 + (mnb >> 5)], 1u << (mnb & 31));
    }
    __syncthreads();

    // ---- write masks: 16 rows x 6 words, coalesced ----
    if (tid < 96) {
        const int pl = tid / 6, c = tid % 6;
        sel_out[p0 * 6 + tid] = selS[pl * 8 + c];
    }
}

// ---------------- K2: select GEMM  out[p][d] = SEL[p][mn] * mem[mn][d] ----------------
// grid 256 x 256 thr; block -> 32 p rows (2 ptiles); wave w -> d-tiles 4w..4w+3.
__global__ __launch_bounds__(256) void select_kernel(
    const uint32_t* __restrict__ sel_in,
    const _Float16* __restrict__ bG_h, const _Float16* __restrict__ bG_l,
    float* __restrict__ out)
{
    __shared__ uint32_t selL[32 * 6];

    const int p0   = blockIdx.x * 32;
    const int tid  = threadIdx.x;
    const int lane = tid & 63;
    const int w    = tid >> 6;

    if (tid < 192) selL[tid] = sel_in[p0 * 6 + tid];
    __syncthreads();

    const int q  = lane >> 4, col = lane & 15;
    const int qb = q * 8;

    uint32_t sw[2][6];
#pragma unroll
    for (int pt = 0; pt < 2; ++pt)
#pragma unroll
        for (int c = 0; c < 6; ++c) sw[pt][c] = selL[(pt * 16 + col) * 6 + c];

    f32x4 acc[2][4];
#pragma unroll
    for (int pt = 0; pt < 2; ++pt)
#pragma unroll
        for (int i = 0; i < 4; ++i) acc[pt][i] = (f32x4){0.f, 0.f, 0.f, 0.f};

    const _Float16 ONE = (_Float16)1.f, ZERO = (_Float16)0.f;
#pragma unroll 2
    for (int c = 0; c < 6; ++c) {
        half8 sel[2];
#pragma unroll
        for (int pt = 0; pt < 2; ++pt)
#pragma unroll
            for (int j = 0; j < 8; ++j)
                sel[pt][j] = ((sw[pt][c] >> (qb + j)) & 1u) ? ONE : ZERO;
#pragma unroll
        for (int i = 0; i < 4; ++i) {
            const int td = w * 4 + i;
            const size_t off = (size_t)((td * 6 + c) * 64 + lane) * 8;
            const half8 mh = *(const half8*)(bG_h + off);
            const half8 ml = *(const half8*)(bG_l + off);
#pragma unroll
            for (int pt = 0; pt < 2; ++pt) {
                acc[pt][i] = __builtin_amdgcn_mfma_f32_16x16x32_f16(sel[pt], mh, acc[pt][i], 0, 0, 0);
                acc[pt][i] = __builtin_amdgcn_mfma_f32_16x16x32_f16(sel[pt], ml, acc[pt][i], 0, 0, 0);
            }
        }
    }

#pragma unroll
    for (int pt = 0; pt < 2; ++pt)
#pragma unroll
        for (int i = 0; i < 4; ++i) {
            const int td = w * 4 + i;
#pragma unroll
            for (int r = 0; r < 4; ++r) {
                out[(size_t)(p0 + pt * 16 + q * 4 + r) * DD + td * 16 + col] = acc[pt][i][r];
            }
        }
}

extern "C" void kernel_launch(void* const* d_in, const int* in_sizes, int n_in,
                              void* d_out, int out_size, void* d_ws, size_t ws_size,
                              hipStream_t stream) {
    (void)in_sizes; (void)n_in; (void)out_size; (void)ws_size;
    const float* x    = (const float*)d_in[0];
    const float* mem  = (const float*)d_in[1];
    const float* bias = (const float*)d_in[2];
    float* out = (float*)d_out;

    _Float16* aS_h = (_Float16*)d_ws;
    _Float16* aS_l = aS_h + FRAG_ELEMS;
    _Float16* bG_h = aS_l + FRAG_ELEMS;
    _Float16* bG_l = bG_h + FRAG_ELEMS;
    uint32_t* sel  = (uint32_t*)(bG_l + FRAG_ELEMS);   // 8192*6 u32 = 196 KB

    prep_kernel<<<FRAG_ELEMS / 256, 256, 0, stream>>>(mem, aS_h, aS_l, bG_h, bG_l);
    score_sel_kernel<<<PT / 16, 256, 0, stream>>>(x, bias, aS_h, aS_l, sel);
    select_kernel<<<PT / 32, 256, 0, stream>>>(sel, bG_h, bG_l, out);
}

// Round 6
// 76.024 us; speedup vs baseline: 1.1902x; 1.1902x over previous
//
#include <hip/hip_runtime.h>
#include <stdint.h>

#define LL   2048
#define DD   256
#define SLOTS 64
#define MN   192
#define PT   8192          // B*L

typedef _Float16 half8 __attribute__((ext_vector_type(8)));
typedef float    f32x4 __attribute__((ext_vector_type(4)));

#define FRAG_ELEMS (MN * DD)   // 49152 f16 elems per frag array

// ---------------- K0: fragment prep ----------------
// aS_h/aS_l: mem as A-frags (hi/lo f16) for score GEMM; bG_h: mem as B-frags (hi) for select GEMM.
__global__ __launch_bounds__(256) void prep_kernel(
    const float* __restrict__ mem,
    _Float16* __restrict__ aS_h, _Float16* __restrict__ aS_l,
    _Float16* __restrict__ bG_h)
{
    const int e = blockIdx.x * 256 + threadIdx.x;   // grid 192 -> 49152
    const int mn = e >> 8;
    const int d  = e & 255;
    const float v = mem[e];
    const _Float16 h  = (_Float16)v;
    const _Float16 lo = (_Float16)(v - (float)h);

    // score GEMM A-frags: tiles of 16 mn, K-chunks of 32 d
    {
        const int tm = mn >> 4, r = mn & 15;
        const int c = d >> 5, q = (d >> 3) & 3, j = d & 7;
        const int i1 = ((tm * 8 + c) * 64 + (q * 16 + r)) * 8 + j;
        aS_h[i1] = h; aS_l[i1] = lo;
    }
    // select GEMM B-frags: K-chunks of 32 mn, d-tiles of 16
    {
        const int c2 = mn >> 5, q2 = (mn >> 3) & 3, j2 = mn & 7;
        const int td = d >> 4, n2 = d & 15;
        const int i2 = ((td * 6 + c2) * 64 + (q2 * 16 + n2)) * 8 + j2;
        bG_h[i2] = h;
    }
}

// ---------------- K1: fused score MFMA + argmax + select MFMA ----------------
// grid 512 x 256 thr (4 waves). Block -> 16 output p rows; score window 32 rows.
__global__ __launch_bounds__(256) void fused_kernel(
    const float* __restrict__ x, const float* __restrict__ bias,
    const _Float16* __restrict__ aS_h, const _Float16* __restrict__ aS_l,
    const _Float16* __restrict__ bG_h,
    float* __restrict__ out)
{
    __shared__ _Float16 xfh[2 * 8 * 64 * 8];   // 16 KB
    __shared__ _Float16 xfl[2 * 8 * 64 * 8];   // 16 KB
    __shared__ float    scores[MN * 18];       // 13.5 KB (wp 0..17 only)
    __shared__ float    biasS[MN];
    __shared__ uint32_t selS[16 * 8];
    // total ~46.8 KB -> 3 blocks/CU capacity

    const int p0   = blockIdx.x * 16;
    const int tid  = threadIdx.x;
    const int lane = tid & 63;
    const int w    = tid >> 6;
    const int q    = lane >> 4, col = lane & 15;

    // ---- prefetch phase-B A-frags (c=0) before any barrier (global, no LDS dep) ----
    half8 ah[2][3], al[2][3];
#pragma unroll
    for (int i = 0; i < 3; ++i) {
        const int tm = w * 3 + i;
        const size_t off = (size_t)((tm * 8 + 0) * 64 + lane) * 8;
        ah[0][i] = *(const half8*)(aS_h + off);
        al[0][i] = *(const half8*)(aS_l + off);
    }

    if (tid < 128) selS[tid] = 0u;
    if (tid < MN)  biasS[tid] = bias[tid];

    // ---- Phase A: stage x window -> f16 hi/lo B-frags in LDS ----
    {
        const int c  = tid & 7;
        const int rr = tid >> 3;        // window row 0..31
        int g = p0 - 2 + rr;
        g = g < 0 ? 0 : (g > PT - 1 ? PT - 1 : g);
        const float4* xr = (const float4*)(x + (size_t)g * DD + c * 32);
        const int pt = rr >> 4, lr = rr & 15;
#pragma unroll
        for (int qq = 0; qq < 4; ++qq) {
            const float4 u = xr[qq * 2];
            const float4 v = xr[qq * 2 + 1];
            float f[8] = {u.x, u.y, u.z, u.w, v.x, v.y, v.z, v.w};
            half8 hi, lo;
#pragma unroll
            for (int j = 0; j < 8; ++j) {
                const _Float16 h = (_Float16)f[j];
                hi[j] = h;
                lo[j] = (_Float16)(f[j] - (float)h);
            }
            const int base = ((pt * 8 + c) * 64 + qq * 16 + lr) * 8;
            *(half8*)(xfh + base) = hi;
            *(half8*)(xfl + base) = lo;
        }
    }
    __syncthreads();

    // ---- Phase B: score GEMM, depth-1 pipelined over c ----
    {
        f32x4 acc[3][2];
#pragma unroll
        for (int i = 0; i < 3; ++i)
#pragma unroll
            for (int p = 0; p < 2; ++p) acc[i][p] = (f32x4){0.f, 0.f, 0.f, 0.f};

        half8 bh[2][2], bl[2][2];
#pragma unroll
        for (int p = 0; p < 2; ++p) {
            const int base = ((p * 8 + 0) * 64 + lane) * 8;
            bh[0][p] = *(const half8*)(xfh + base);
            bl[0][p] = *(const half8*)(xfl + base);
        }

#pragma unroll
        for (int c = 0; c < 8; ++c) {
            const int cur = c & 1, nxt = cur ^ 1;
            if (c < 7) {
#pragma unroll
                for (int i = 0; i < 3; ++i) {
                    const int tm = w * 3 + i;
                    const size_t off = (size_t)((tm * 8 + c + 1) * 64 + lane) * 8;
                    ah[nxt][i] = *(const half8*)(aS_h + off);
                    al[nxt][i] = *(const half8*)(aS_l + off);
                }
#pragma unroll
                for (int p = 0; p < 2; ++p) {
                    const int base = ((p * 8 + c + 1) * 64 + lane) * 8;
                    bh[nxt][p] = *(const half8*)(xfh + base);
                    bl[nxt][p] = *(const half8*)(xfl + base);
                }
            }
#pragma unroll
            for (int i = 0; i < 3; ++i)
#pragma unroll
                for (int p = 0; p < 2; ++p) {
                    acc[i][p] = __builtin_amdgcn_mfma_f32_16x16x32_f16(ah[cur][i], bh[cur][p], acc[i][p], 0, 0, 0);
                    acc[i][p] = __builtin_amdgcn_mfma_f32_16x16x32_f16(ah[cur][i], bl[cur][p], acc[i][p], 0, 0, 0);
                    acc[i][p] = __builtin_amdgcn_mfma_f32_16x16x32_f16(al[cur][i], bh[cur][p], acc[i][p], 0, 0, 0);
                }
        }

        // store scores, only window cols 0..17 (stride 18; max 2-way bank alias)
#pragma unroll
        for (int i = 0; i < 3; ++i) {
            const int tm = w * 3 + i;
#pragma unroll
            for (int p = 0; p < 2; ++p) {
                const int wp = p * 16 + col;
                if (wp < 18) {
#pragma unroll
                    for (int r = 0; r < 4; ++r)
                        scores[(tm * 16 + q * 4 + r) * 18 + wp] = acc[i][p][r];
                }
            }
        }
    }

    // ---- prefetch phase-D B-frags (c=0) before the barrier ----
    half8 mg[2][4];
#pragma unroll
    for (int i = 0; i < 4; ++i) {
        const int td = w * 4 + i;
        const size_t off = (size_t)((td * 6 + 0) * 64 + lane) * 8;
        mg[0][i] = *(const half8*)(bG_h + off);
    }
    __syncthreads();

    // ---- Phase C: argmax over n (first-max tiebreak) -> selection bitmask ----
#pragma unroll
    for (int it = 0; it < 4; ++it) {
        const int t2 = tid + it * 256;
        const int pl = t2 & 15;
        const int m  = t2 >> 4;
        const int p  = p0 + pl;
        const int l  = p & (LL - 1);
        const float v0 = ((l >= 2) ? scores[(3 * m + 0) * 18 + pl + 0] : 0.f) + biasS[3 * m + 0];
        const float v1 = ((l >= 1) ? scores[(3 * m + 1) * 18 + pl + 1] : 0.f) + biasS[3 * m + 1];
        const float v2 =              scores[(3 * m + 2) * 18 + pl + 2]       + biasS[3 * m + 2];
        int bn = 0; float bv = v0;
        if (v1 > bv) { bv = v1; bn = 1; }
        if (v2 > bv) { bv = v2; bn = 2; }
        const int mnb = 3 * m + bn;
        atomicOr(&selS[pl * 8 + (mnb >> 5)], 1u << (mnb & 31));
    }
    __syncthreads();

    // ---- Phase D: select GEMM (f16 hi only), depth-1 pipelined ----
    {
        uint32_t sw[6];
#pragma unroll
        for (int c = 0; c < 6; ++c) sw[c] = selS[col * 8 + c];

        f32x4 acc2[4];
#pragma unroll
        for (int i = 0; i < 4; ++i) acc2[i] = (f32x4){0.f, 0.f, 0.f, 0.f};

        const _Float16 ONE = (_Float16)1.f, ZERO = (_Float16)0.f;
        const int qb = q * 8;
#pragma unroll
        for (int c = 0; c < 6; ++c) {
            const int cur = c & 1, nxt = cur ^ 1;
            if (c < 5) {
#pragma unroll
                for (int i = 0; i < 4; ++i) {
                    const int td = w * 4 + i;
                    const size_t off = (size_t)((td * 6 + c + 1) * 64 + lane) * 8;
                    mg[nxt][i] = *(const half8*)(bG_h + off);
                }
            }
            half8 sel;
#pragma unroll
            for (int j = 0; j < 8; ++j)
                sel[j] = ((sw[c] >> (qb + j)) & 1u) ? ONE : ZERO;
#pragma unroll
            for (int i = 0; i < 4; ++i)
                acc2[i] = __builtin_amdgcn_mfma_f32_16x16x32_f16(sel, mg[cur][i], acc2[i], 0, 0, 0);
        }

#pragma unroll
        for (int i = 0; i < 4; ++i) {
            const int td = w * 4 + i;
#pragma unroll
            for (int r = 0; r < 4; ++r)
                out[(size_t)(p0 + q * 4 + r) * DD + td * 16 + col] = acc2[i][r];
        }
    }
}

extern "C" void kernel_launch(void* const* d_in, const int* in_sizes, int n_in,
                              void* d_out, int out_size, void* d_ws, size_t ws_size,
                              hipStream_t stream) {
    (void)in_sizes; (void)n_in; (void)out_size; (void)ws_size;
    const float* x    = (const float*)d_in[0];
    const float* mem  = (const float*)d_in[1];
    const float* bias = (const float*)d_in[2];
    float* out = (float*)d_out;

    _Float16* aS_h = (_Float16*)d_ws;
    _Float16* aS_l = aS_h + FRAG_ELEMS;
    _Float16* bG_h = aS_l + FRAG_ELEMS;

    prep_kernel<<<FRAG_ELEMS / 256, 256, 0, stream>>>(mem, aS_h, aS_l, bG_h);
    fused_kernel<<<PT / 16, 256, 0, stream>>>(x, bias, aS_h, aS_l, bG_h, out);
}